// Round 1
// baseline (2330.373 us; speedup 1.0000x reference)
//
#include <hip/hip_runtime.h>
#include <hip/hip_bf16.h>

#define IN_DIM 128
#define HID 64
#define NEG_SLOPE 0.01f

__device__ __forceinline__ float fsig(float x) { return 1.f / (1.f + __expf(-x)); }
__device__ __forceinline__ float ftanh(float x) { return 1.f - 2.f / (__expf(2.f * x) + 1.f); }

// ---- graph normalization ----------------------------------------------------
__global__ void deg_kernel(const int* __restrict__ src, const float* __restrict__ ew,
                           float* __restrict__ deg, int E) {
    int e = blockIdx.x * blockDim.x + threadIdx.x;
    if (e < E) atomicAdd(&deg[src[e]], ew[e]);
}

__global__ void dinv_kernel(const float* __restrict__ deg, float* __restrict__ dinv, int N) {
    int n = blockIdx.x * blockDim.x + threadIdx.x;
    if (n < N) {
        float d = deg[n];
        dinv[n] = d > 0.f ? rsqrtf(d) : 0.f;
    }
}

__global__ void norm_kernel(const int* __restrict__ src, const int* __restrict__ dst,
                            const float* __restrict__ ew, const float* __restrict__ dinv,
                            float* __restrict__ nrm, int E) {
    int e = blockIdx.x * blockDim.x + threadIdx.x;
    if (e < E) nrm[e] = -dinv[src[e]] * ew[e] * dinv[dst[e]];
}

// ---- propagation: Tx[dst] += nrm * x[src] (atomic scatter) ------------------
__global__ void scatter_x_kernel(const int* __restrict__ src, const int* __restrict__ dst,
                                 const float* __restrict__ nrm, const float* __restrict__ x,
                                 float* __restrict__ Tx, int E) {
    int t = blockIdx.x * blockDim.x + threadIdx.x;
    if (t >= E * 32) return;
    int e = t >> 5, q = t & 31;
    float w = nrm[e];
    if (w == 0.f) return;
    float4 v = ((const float4*)x)[src[e] * 32 + q];
    float* p = Tx + (size_t)dst[e] * 128 + q * 4;
    atomicAdd(p + 0, w * v.x);
    atomicAdd(p + 1, w * v.y);
    atomicAdd(p + 2, w * v.z);
    atomicAdd(p + 3, w * v.w);
}

__global__ void scatter_h_kernel(const int* __restrict__ src, const int* __restrict__ dst,
                                 const float* __restrict__ nrm, const float* __restrict__ h,
                                 float* __restrict__ Th, int E) {
    int t = blockIdx.x * blockDim.x + threadIdx.x;
    if (t >= E * 16) return;
    int e = t >> 4, q = t & 15;
    float w = nrm[e];
    if (w == 0.f) return;
    float4 v = ((const float4*)h)[src[e] * 16 + q];
    float* p = Th + (size_t)dst[e] * 64 + q * 4;
    atomicAdd(p + 0, w * v.x);
    atomicAdd(p + 1, w * v.y);
    atomicAdd(p + 2, w * v.z);
    atomicAdd(p + 3, w * v.w);
}

// ---- pack weights: Wt[r][hd][g], r = [Wx0(128) | Wh0(64) | Wx1(128) | Wh1(64)]
__global__ void pack_w_kernel(const float* __restrict__ Wx, const float* __restrict__ Wh,
                              float* __restrict__ Wt) {
    int idx = blockIdx.x * blockDim.x + threadIdx.x;
    if (idx >= 384 * 256) return;
    int r = idx >> 8;
    int c = idx & 255;
    int hd = c >> 2, g = c & 3;
    float v;
    if (r < 128)      v = Wx[((g * 2 + 0) * 128 + r) * 64 + hd];
    else if (r < 192) v = Wh[((g * 2 + 0) * 64 + (r - 128)) * 64 + hd];
    else if (r < 320) v = Wx[((g * 2 + 1) * 128 + (r - 192)) * 64 + hd];
    else              v = Wh[((g * 2 + 1) * 64 + (r - 320)) * 64 + hd];
    Wt[idx] = v;
}

// ---- fused GEMM (N x 384 @ 384 x 256) + LSTM gates + head -------------------
// block = 256 threads = 4 waves; each wave handles 8 nodes, lane = hd (0..63),
// each thread accumulates all 4 gates for its (node, hd) pairs.
__global__ __launch_bounds__(256) void fused_main(
    const float* __restrict__ x, const float* __restrict__ h, const float* __restrict__ c_in,
    const float* __restrict__ Tx, const float* __restrict__ Th, const float* __restrict__ Wt,
    const float* __restrict__ bx, const float* __restrict__ bh, const float* __restrict__ wc,
    const float* __restrict__ bg, const float* __restrict__ Whead, const float* __restrict__ bhead,
    float* __restrict__ out, int N) {
    __shared__ float As[32 * 388];  // 32 nodes x 384 feats, +4 pad
    int n0 = blockIdx.x * 32;
    int tid = threadIdx.x;

    const float4* x4 = (const float4*)x;
    const float4* h4 = (const float4*)h;
    const float4* Tx4 = (const float4*)Tx;
    const float4* Th4 = (const float4*)Th;

    // cooperative A-tile load: per node row = [x(32 f4) | h(16 f4) | Tx(32 f4) | Th(16 f4)]
    for (int i = tid; i < 32 * 96; i += 256) {
        int m = i / 96, q = i - m * 96;
        int n = n0 + m;
        float4 v = make_float4(0.f, 0.f, 0.f, 0.f);
        if (n < N) {
            if (q < 32)      v = x4[n * 32 + q];
            else if (q < 48) v = h4[n * 16 + (q - 32)];
            else if (q < 80) v = Tx4[n * 32 + (q - 48)];
            else             v = Th4[n * 16 + (q - 80)];
        }
        *(float4*)(&As[m * 388 + q * 4]) = v;
    }
    __syncthreads();

    int tx = tid & 63;   // hd
    int ty = tid >> 6;   // wave id -> node group

    float acc[8][4];
#pragma unroll
    for (int g = 0; g < 4; ++g) {
        float b = bx[g * 64 + tx] + bh[g * 64 + tx];
#pragma unroll
        for (int mm = 0; mm < 8; ++mm) acc[mm][g] = b;
    }

    const float4* Wt4 = (const float4*)Wt;
    for (int r = 0; r < 384; r += 4) {
        float4 w0 = Wt4[(r + 0) * 64 + tx];
        float4 w1 = Wt4[(r + 1) * 64 + tx];
        float4 w2 = Wt4[(r + 2) * 64 + tx];
        float4 w3 = Wt4[(r + 3) * 64 + tx];
#pragma unroll
        for (int mm = 0; mm < 8; ++mm) {
            float4 a = *(const float4*)(&As[(ty * 8 + mm) * 388 + r]);
            acc[mm][0] += a.x * w0.x + a.y * w1.x + a.z * w2.x + a.w * w3.x;
            acc[mm][1] += a.x * w0.y + a.y * w1.y + a.z * w2.y + a.w * w3.y;
            acc[mm][2] += a.x * w0.z + a.y * w1.z + a.z * w2.z + a.w * w3.z;
            acc[mm][3] += a.x * w0.w + a.y * w1.w + a.z * w2.w + a.w * w3.w;
        }
    }

    float wc0 = wc[0 * 64 + tx], wc1 = wc[1 * 64 + tx], wc2 = wc[2 * 64 + tx];
    float bg0 = bg[0 * 64 + tx], bg1 = bg[1 * 64 + tx], bg2 = bg[2 * 64 + tx], bg3 = bg[3 * 64 + tx];
    float wh = Whead[tx];

#pragma unroll
    for (int mm = 0; mm < 8; ++mm) {
        int n = n0 + ty * 8 + mm;
        if (n < N) {
            float c_old = c_in[n * 64 + tx];
            float ii = fsig(acc[mm][0] + wc0 * c_old + bg0);
            float ff = fsig(acc[mm][1] + wc1 * c_old + bg1);
            float gg = ftanh(acc[mm][2] + bg2);
            float c_new = ff * c_old + ii * gg;
            float oo = fsig(acc[mm][3] + wc2 * c_new + bg3);
            float h_new = oo * ftanh(c_new);
            out[N + (size_t)n * 64 + tx] = h_new;
            out[N + (size_t)N * 64 + (size_t)n * 64 + tx] = c_new;
            float lr = h_new > 0.f ? h_new : NEG_SLOPE * h_new;
            float val = lr * wh;
#pragma unroll
            for (int off = 32; off; off >>= 1) val += __shfl_down(val, off);
            if (tx == 0) out[n] = val + bhead[0];
        }
    }
}

extern "C" void kernel_launch(void* const* d_in, const int* in_sizes, int n_in,
                              void* d_out, int out_size, void* d_ws, size_t ws_size,
                              hipStream_t stream) {
    const float* x = (const float*)d_in[0];
    const int* ei = (const int*)d_in[1];
    const float* ew = (const float*)d_in[2];
    const float* h = (const float*)d_in[3];
    const float* c = (const float*)d_in[4];
    const float* Wx = (const float*)d_in[5];
    const float* bx = (const float*)d_in[6];
    const float* Wh = (const float*)d_in[7];
    const float* bh = (const float*)d_in[8];
    const float* wc = (const float*)d_in[9];
    const float* bg = (const float*)d_in[10];
    const float* Whead = (const float*)d_in[11];
    const float* bhead = (const float*)d_in[12];

    int N = in_sizes[0] / IN_DIM;  // 50000
    int E = in_sizes[1] / 2;       // 800000
    const int* src = ei;
    const int* dst = ei + E;

    float* ws = (float*)d_ws;
    float* deg = ws;                         // N
    float* Tx = deg + N;                     // N*128
    float* Th = Tx + (size_t)N * 128;        // N*64
    float* dinv = Th + (size_t)N * 64;       // N
    float* nrm = dinv + N;                   // E
    float* Wt = nrm + E;                     // 384*256

    // zero-init the atomic accumulation region: [deg | Tx | Th]
    hipMemsetAsync(deg, 0, (size_t)(N + (size_t)N * 128 + (size_t)N * 64) * sizeof(float), stream);

    deg_kernel<<<(E + 255) / 256, 256, 0, stream>>>(src, ew, deg, E);
    dinv_kernel<<<(N + 255) / 256, 256, 0, stream>>>(deg, dinv, N);
    norm_kernel<<<(E + 255) / 256, 256, 0, stream>>>(src, dst, ew, dinv, nrm, E);
    pack_w_kernel<<<(384 * 256 + 255) / 256, 256, 0, stream>>>(Wx, Wh, Wt);
    scatter_x_kernel<<<(E * 32 + 255) / 256, 256, 0, stream>>>(src, dst, nrm, x, Tx, E);
    scatter_h_kernel<<<(E * 16 + 255) / 256, 256, 0, stream>>>(src, dst, nrm, h, Th, E);
    fused_main<<<(N + 31) / 32, 256, 0, stream>>>(x, h, c, Tx, Th, Wt, bx, bh, wc, bg,
                                                  Whead, bhead, (float*)d_out, N);
}

// Round 2
// 494.485 us; speedup vs baseline: 4.7127x; 4.7127x over previous
//
#include <hip/hip_runtime.h>
#include <hip/hip_bf16.h>

#define IN_DIM 128
#define HID 64
#define NEG_SLOPE 0.01f

__device__ __forceinline__ float fsig(float x) { return 1.f / (1.f + __expf(-x)); }
__device__ __forceinline__ float ftanh(float x) { return 1.f - 2.f / (__expf(2.f * x) + 1.f); }

// ---- degree (by src, float) + histogram (by dst, int) -----------------------
__global__ void deg_hist_kernel(const int* __restrict__ src, const int* __restrict__ dst,
                                const float* __restrict__ ew, float* __restrict__ deg,
                                int* __restrict__ cnt, int E) {
    int e = blockIdx.x * blockDim.x + threadIdx.x;
    if (e < E) {
        atomicAdd(&deg[src[e]], ew[e]);
        atomicAdd(&cnt[dst[e]], 1);
    }
}

__global__ void dinv_kernel(const float* __restrict__ deg, float* __restrict__ dinv, int N) {
    int n = blockIdx.x * blockDim.x + threadIdx.x;
    if (n < N) {
        float d = deg[n];
        dinv[n] = d > 0.f ? rsqrtf(d) : 0.f;
    }
}

// ---- 3-kernel exclusive scan over cnt[0..N-1] (scan length N+1) -------------
// scan1: per-block (1024 elems) exclusive scan + block sums
__global__ __launch_bounds__(256) void scan1_kernel(const int* __restrict__ cnt,
                                                    int* __restrict__ rowptr,
                                                    int* __restrict__ bsum, int n, int N) {
    __shared__ int sdata[256];
    int b = blockIdx.x, t = threadIdx.x;
    int base = b * 1024 + t * 4;
    int v[4];
    int tsum = 0;
#pragma unroll
    for (int j = 0; j < 4; ++j) {
        int idx = base + j;
        v[j] = (idx < N) ? cnt[idx] : 0;  // element N (and beyond) = 0
        tsum += v[j];
    }
    sdata[t] = tsum;
    __syncthreads();
    for (int off = 1; off < 256; off <<= 1) {
        int tmp = (t >= off) ? sdata[t - off] : 0;
        __syncthreads();
        sdata[t] += tmp;
        __syncthreads();
    }
    if (t == 255) bsum[b] = sdata[255];
    int run = sdata[t] - tsum;  // exclusive prefix of this thread's chunk
#pragma unroll
    for (int j = 0; j < 4; ++j) {
        int idx = base + j;
        if (idx < n) rowptr[idx] = run;  // n = N+1
        run += v[j];
    }
}

// scan2: sequential exclusive scan of block sums (tiny)
__global__ void scan2_kernel(int* __restrict__ bsum, int nb) {
    if (threadIdx.x == 0 && blockIdx.x == 0) {
        int run = 0;
        for (int i = 0; i < nb; ++i) {
            int v = bsum[i];
            bsum[i] = run;
            run += v;
        }
    }
}

// scan3: add block offsets
__global__ void scan3_kernel(int* __restrict__ rowptr, const int* __restrict__ bsum, int n) {
    int i = blockIdx.x * blockDim.x + threadIdx.x;
    if (i < n) rowptr[i] += bsum[i >> 10];
}

// ---- fill CSR: esrc/enrm sorted by dst --------------------------------------
__global__ void fill_kernel(const int* __restrict__ src, const int* __restrict__ dst,
                            const float* __restrict__ ew, const float* __restrict__ dinv,
                            const int* __restrict__ rowptr, int* __restrict__ fill,
                            int* __restrict__ esrc, float* __restrict__ enrm, int E) {
    int e = blockIdx.x * blockDim.x + threadIdx.x;
    if (e < E) {
        int d = dst[e];
        int s = src[e];
        int pos = rowptr[d] + atomicAdd(&fill[d], 1);
        esrc[pos] = s;
        enrm[pos] = -dinv[s] * ew[e] * dinv[d];
    }
}

// ---- gather: Tx[n] = sum_e nrm*x[src], Th[n] = sum_e nrm*h[src] -------------
// one wave per node; lane covers 2 x-dims (float2) + 1 h-dim
__global__ __launch_bounds__(256) void gather_kernel(const int* __restrict__ rowptr,
                                                     const int* __restrict__ esrc,
                                                     const float* __restrict__ enrm,
                                                     const float* __restrict__ x,
                                                     const float* __restrict__ h,
                                                     float* __restrict__ Tx,
                                                     float* __restrict__ Th, int N) {
    int node = blockIdx.x * 4 + (threadIdx.x >> 6);
    int lane = threadIdx.x & 63;
    if (node >= N) return;
    int p = rowptr[node], end = rowptr[node + 1];
    const float2* x2 = (const float2*)x;
    float ax = 0.f, ay = 0.f, ah = 0.f;
    for (; p + 1 < end; p += 2) {
        int s0 = esrc[p], s1 = esrc[p + 1];
        float w0 = enrm[p], w1 = enrm[p + 1];
        float2 xv0 = x2[s0 * 64 + lane];
        float2 xv1 = x2[s1 * 64 + lane];
        float hv0 = h[s0 * 64 + lane];
        float hv1 = h[s1 * 64 + lane];
        ax += w0 * xv0.x + w1 * xv1.x;
        ay += w0 * xv0.y + w1 * xv1.y;
        ah += w0 * hv0 + w1 * hv1;
    }
    if (p < end) {
        int s0 = esrc[p];
        float w0 = enrm[p];
        float2 xv0 = x2[s0 * 64 + lane];
        ax += w0 * xv0.x;
        ay += w0 * xv0.y;
        ah += w0 * h[s0 * 64 + lane];
    }
    ((float2*)Tx)[node * 64 + lane] = make_float2(ax, ay);
    Th[node * 64 + lane] = ah;
}

// ---- pack weights: Wt[r][hd][g], r = [Wx0(128) | Wh0(64) | Wx1(128) | Wh1(64)]
__global__ void pack_w_kernel(const float* __restrict__ Wx, const float* __restrict__ Wh,
                              float* __restrict__ Wt) {
    int idx = blockIdx.x * blockDim.x + threadIdx.x;
    if (idx >= 384 * 256) return;
    int r = idx >> 8;
    int c = idx & 255;
    int hd = c >> 2, g = c & 3;
    float v;
    if (r < 128)      v = Wx[((g * 2 + 0) * 128 + r) * 64 + hd];
    else if (r < 192) v = Wh[((g * 2 + 0) * 64 + (r - 128)) * 64 + hd];
    else if (r < 320) v = Wx[((g * 2 + 1) * 128 + (r - 192)) * 64 + hd];
    else              v = Wh[((g * 2 + 1) * 64 + (r - 320)) * 64 + hd];
    Wt[idx] = v;
}

// ---- fused GEMM (N x 384 @ 384 x 256) + LSTM gates + head -------------------
__global__ __launch_bounds__(256) void fused_main(
    const float* __restrict__ x, const float* __restrict__ h, const float* __restrict__ c_in,
    const float* __restrict__ Tx, const float* __restrict__ Th, const float* __restrict__ Wt,
    const float* __restrict__ bx, const float* __restrict__ bh, const float* __restrict__ wc,
    const float* __restrict__ bg, const float* __restrict__ Whead, const float* __restrict__ bhead,
    float* __restrict__ out, int N) {
    __shared__ float As[32 * 388];  // 32 nodes x 384 feats, +4 pad
    int n0 = blockIdx.x * 32;
    int tid = threadIdx.x;

    const float4* x4 = (const float4*)x;
    const float4* h4 = (const float4*)h;
    const float4* Tx4 = (const float4*)Tx;
    const float4* Th4 = (const float4*)Th;

    for (int i = tid; i < 32 * 96; i += 256) {
        int m = i / 96, q = i - m * 96;
        int n = n0 + m;
        float4 v = make_float4(0.f, 0.f, 0.f, 0.f);
        if (n < N) {
            if (q < 32)      v = x4[n * 32 + q];
            else if (q < 48) v = h4[n * 16 + (q - 32)];
            else if (q < 80) v = Tx4[n * 32 + (q - 48)];
            else             v = Th4[n * 16 + (q - 80)];
        }
        *(float4*)(&As[m * 388 + q * 4]) = v;
    }
    __syncthreads();

    int tx = tid & 63;   // hd
    int ty = tid >> 6;   // wave id -> node group

    float acc[8][4];
#pragma unroll
    for (int g = 0; g < 4; ++g) {
        float b = bx[g * 64 + tx] + bh[g * 64 + tx];
#pragma unroll
        for (int mm = 0; mm < 8; ++mm) acc[mm][g] = b;
    }

    const float4* Wt4 = (const float4*)Wt;
    for (int r = 0; r < 384; r += 4) {
        float4 w0 = Wt4[(r + 0) * 64 + tx];
        float4 w1 = Wt4[(r + 1) * 64 + tx];
        float4 w2 = Wt4[(r + 2) * 64 + tx];
        float4 w3 = Wt4[(r + 3) * 64 + tx];
#pragma unroll
        for (int mm = 0; mm < 8; ++mm) {
            float4 a = *(const float4*)(&As[(ty * 8 + mm) * 388 + r]);
            acc[mm][0] += a.x * w0.x + a.y * w1.x + a.z * w2.x + a.w * w3.x;
            acc[mm][1] += a.x * w0.y + a.y * w1.y + a.z * w2.y + a.w * w3.y;
            acc[mm][2] += a.x * w0.z + a.y * w1.z + a.z * w2.z + a.w * w3.z;
            acc[mm][3] += a.x * w0.w + a.y * w1.w + a.z * w2.w + a.w * w3.w;
        }
    }

    float wc0 = wc[0 * 64 + tx], wc1 = wc[1 * 64 + tx], wc2 = wc[2 * 64 + tx];
    float bg0 = bg[0 * 64 + tx], bg1 = bg[1 * 64 + tx], bg2 = bg[2 * 64 + tx], bg3 = bg[3 * 64 + tx];
    float wh = Whead[tx];

#pragma unroll
    for (int mm = 0; mm < 8; ++mm) {
        int n = n0 + ty * 8 + mm;
        if (n < N) {
            float c_old = c_in[n * 64 + tx];
            float ii = fsig(acc[mm][0] + wc0 * c_old + bg0);
            float ff = fsig(acc[mm][1] + wc1 * c_old + bg1);
            float gg = ftanh(acc[mm][2] + bg2);
            float c_new = ff * c_old + ii * gg;
            float oo = fsig(acc[mm][3] + wc2 * c_new + bg3);
            float h_new = oo * ftanh(c_new);
            out[N + (size_t)n * 64 + tx] = h_new;
            out[N + (size_t)N * 64 + (size_t)n * 64 + tx] = c_new;
            float lr = h_new > 0.f ? h_new : NEG_SLOPE * h_new;
            float val = lr * wh;
#pragma unroll
            for (int off = 32; off; off >>= 1) val += __shfl_down(val, off);
            if (tx == 0) out[n] = val + bhead[0];
        }
    }
}

extern "C" void kernel_launch(void* const* d_in, const int* in_sizes, int n_in,
                              void* d_out, int out_size, void* d_ws, size_t ws_size,
                              hipStream_t stream) {
    const float* x = (const float*)d_in[0];
    const int* ei = (const int*)d_in[1];
    const float* ew = (const float*)d_in[2];
    const float* h = (const float*)d_in[3];
    const float* c = (const float*)d_in[4];
    const float* Wx = (const float*)d_in[5];
    const float* bx = (const float*)d_in[6];
    const float* Wh = (const float*)d_in[7];
    const float* bh = (const float*)d_in[8];
    const float* wc = (const float*)d_in[9];
    const float* bg = (const float*)d_in[10];
    const float* Whead = (const float*)d_in[11];
    const float* bhead = (const float*)d_in[12];

    int N = in_sizes[0] / IN_DIM;  // 50000
    int E = in_sizes[1] / 2;       // 800000
    const int* src = ei;
    const int* dst = ei + E;

    char* ws = (char*)d_ws;
    float* deg = (float*)ws;                       ws += (size_t)N * 4;
    int* cnt = (int*)ws;                           ws += (size_t)N * 4;
    int* fill = (int*)ws;                          ws += (size_t)N * 4;
    float* dinv = (float*)ws;                      ws += (size_t)N * 4;
    int* rowptr = (int*)ws;                        ws += (size_t)(N + 2) * 4;
    int* bsum = (int*)ws;                          ws += 64 * 4;
    int* esrc = (int*)ws;                          ws += (size_t)E * 4;
    float* enrm = (float*)ws;                      ws += (size_t)E * 4;
    float* Tx = (float*)ws;                        ws += (size_t)N * 128 * 4;
    float* Th = (float*)ws;                        ws += (size_t)N * 64 * 4;
    float* Wt = (float*)ws;                        ws += 384 * 256 * 4;

    // zero only deg | cnt | fill (contiguous, 3N elems)
    hipMemsetAsync(deg, 0, (size_t)3 * N * sizeof(float), stream);

    int nScan = N + 1;
    int nBlocksScan = (nScan + 1023) / 1024;

    deg_hist_kernel<<<(E + 255) / 256, 256, 0, stream>>>(src, dst, ew, deg, cnt, E);
    dinv_kernel<<<(N + 255) / 256, 256, 0, stream>>>(deg, dinv, N);
    scan1_kernel<<<nBlocksScan, 256, 0, stream>>>(cnt, rowptr, bsum, nScan, N);
    scan2_kernel<<<1, 64, 0, stream>>>(bsum, nBlocksScan);
    scan3_kernel<<<(nScan + 255) / 256, 256, 0, stream>>>(rowptr, bsum, nScan);
    fill_kernel<<<(E + 255) / 256, 256, 0, stream>>>(src, dst, ew, dinv, rowptr, fill, esrc, enrm, E);
    pack_w_kernel<<<(384 * 256 + 255) / 256, 256, 0, stream>>>(Wx, Wh, Wt);
    gather_kernel<<<(N + 3) / 4, 256, 0, stream>>>(rowptr, esrc, enrm, x, h, Tx, Th, N);
    fused_main<<<(N + 31) / 32, 256, 0, stream>>>(x, h, c, Tx, Th, Wt, bx, bh, wc, bg,
                                                  Whead, bhead, (float*)d_out, N);
}

// Round 3
// 414.583 us; speedup vs baseline: 5.6210x; 1.1927x over previous
//
#include <hip/hip_runtime.h>
#include <hip/hip_bf16.h>

#define IN_DIM 128
#define HID 64
#define NEG_SLOPE 0.01f

typedef __attribute__((ext_vector_type(8))) short short8;
typedef __attribute__((ext_vector_type(4))) float f32x4;
typedef unsigned short ushort_t;
typedef unsigned int uint_t;

__device__ __forceinline__ float fsig(float x) { return 1.f / (1.f + __expf(-x)); }
__device__ __forceinline__ float ftanh(float x) { return 1.f - 2.f / (__expf(2.f * x) + 1.f); }

__device__ __forceinline__ ushort_t f2bf(float f) {
    uint_t u = __float_as_uint(f);
    uint_t r = u + 0x7fffu + ((u >> 16) & 1u);  // round-to-nearest-even
    return (ushort_t)(r >> 16);
}
__device__ __forceinline__ float bf2f(ushort_t s) { return __uint_as_float(((uint_t)s) << 16); }

// ---- convert x,h to bf16 ----------------------------------------------------
// threads [0, N*64): x pair i -> xb_u[i];  [N*64, N*96): h pair j -> hb_u[j]
__global__ void cvt_kernel(const float* __restrict__ x, const float* __restrict__ h,
                           uint_t* __restrict__ xb_u, uint_t* __restrict__ hb_u, int N) {
    int i = blockIdx.x * blockDim.x + threadIdx.x;
    int nx = N * 64;
    if (i < nx) {
        float2 v = ((const float2*)x)[i];
        xb_u[i] = (uint_t)f2bf(v.x) | ((uint_t)f2bf(v.y) << 16);
    } else if (i < N * 96) {
        int j = i - nx;
        float2 v = ((const float2*)h)[j];
        hb_u[j] = (uint_t)f2bf(v.x) | ((uint_t)f2bf(v.y) << 16);
    }
}

// ---- degree (by src, float) + histogram (by dst, int) -----------------------
__global__ void deg_hist_kernel(const int* __restrict__ src, const int* __restrict__ dst,
                                const float* __restrict__ ew, float* __restrict__ deg,
                                int* __restrict__ cnt, int E) {
    int e = blockIdx.x * blockDim.x + threadIdx.x;
    if (e < E) {
        atomicAdd(&deg[src[e]], ew[e]);
        atomicAdd(&cnt[dst[e]], 1);
    }
}

__global__ void dinv_kernel(const float* __restrict__ deg, float* __restrict__ dinv, int N) {
    int n = blockIdx.x * blockDim.x + threadIdx.x;
    if (n < N) {
        float d = deg[n];
        dinv[n] = d > 0.f ? rsqrtf(d) : 0.f;
    }
}

// ---- 3-kernel exclusive scan over cnt[0..N-1] (scan length N+1) -------------
__global__ __launch_bounds__(256) void scan1_kernel(const int* __restrict__ cnt,
                                                    int* __restrict__ rowptr,
                                                    int* __restrict__ bsum, int n, int N) {
    __shared__ int sdata[256];
    int b = blockIdx.x, t = threadIdx.x;
    int base = b * 1024 + t * 4;
    int v[4];
    int tsum = 0;
#pragma unroll
    for (int j = 0; j < 4; ++j) {
        int idx = base + j;
        v[j] = (idx < N) ? cnt[idx] : 0;
        tsum += v[j];
    }
    sdata[t] = tsum;
    __syncthreads();
    for (int off = 1; off < 256; off <<= 1) {
        int tmp = (t >= off) ? sdata[t - off] : 0;
        __syncthreads();
        sdata[t] += tmp;
        __syncthreads();
    }
    if (t == 255) bsum[b] = sdata[255];
    int run = sdata[t] - tsum;
#pragma unroll
    for (int j = 0; j < 4; ++j) {
        int idx = base + j;
        if (idx < n) rowptr[idx] = run;
        run += v[j];
    }
}

__global__ void scan2_kernel(int* __restrict__ bsum, int nb) {
    if (threadIdx.x == 0 && blockIdx.x == 0) {
        int run = 0;
        for (int i = 0; i < nb; ++i) {
            int v = bsum[i];
            bsum[i] = run;
            run += v;
        }
    }
}

__global__ void scan3_kernel(int* __restrict__ rowptr, const int* __restrict__ bsum, int n) {
    int i = blockIdx.x * blockDim.x + threadIdx.x;
    if (i < n) rowptr[i] += bsum[i >> 10];
}

// ---- fill CSR: esrc/enrm sorted by dst --------------------------------------
__global__ void fill_kernel(const int* __restrict__ src, const int* __restrict__ dst,
                            const float* __restrict__ ew, const float* __restrict__ dinv,
                            const int* __restrict__ rowptr, int* __restrict__ fill,
                            int* __restrict__ esrc, float* __restrict__ enrm, int E) {
    int e = blockIdx.x * blockDim.x + threadIdx.x;
    if (e < E) {
        int d = dst[e];
        int s = src[e];
        int pos = rowptr[d] + atomicAdd(&fill[d], 1);
        esrc[pos] = s;
        enrm[pos] = -dinv[s] * ew[e] * dinv[d];
    }
}

// ---- gather: Txb[n] = sum_e nrm*xb[src], Thb[n] = sum_e nrm*hb[src] (bf16 io)
// one wave per node; lane covers 2 x-dims (packed uint) + 1 h-dim
__global__ __launch_bounds__(256) void gather_kernel(const int* __restrict__ rowptr,
                                                     const int* __restrict__ esrc,
                                                     const float* __restrict__ enrm,
                                                     const uint_t* __restrict__ xb_u,
                                                     const ushort_t* __restrict__ hb,
                                                     uint_t* __restrict__ Txb_u,
                                                     ushort_t* __restrict__ Thb, int N) {
    int node = blockIdx.x * 4 + (threadIdx.x >> 6);
    int lane = threadIdx.x & 63;
    if (node >= N) return;
    int p = rowptr[node], end = rowptr[node + 1];
    float ax = 0.f, ay = 0.f, ah = 0.f;
    for (int base = p; base < end; base += 64) {
        int m = end - base; if (m > 64) m = 64;
        int sv = (base + lane < end) ? esrc[base + lane] : 0;
        float wv = (base + lane < end) ? enrm[base + lane] : 0.f;
        int j = 0;
        for (; j + 2 <= m; j += 2) {
            int s0 = __shfl(sv, j);     float w0 = __shfl(wv, j);
            int s1 = __shfl(sv, j + 1); float w1 = __shfl(wv, j + 1);
            uint_t xv0 = xb_u[(size_t)s0 * 64 + lane];
            uint_t xv1 = xb_u[(size_t)s1 * 64 + lane];
            ushort_t hv0 = hb[(size_t)s0 * 64 + lane];
            ushort_t hv1 = hb[(size_t)s1 * 64 + lane];
            ax += w0 * bf2f((ushort_t)(xv0 & 0xffff)) + w1 * bf2f((ushort_t)(xv1 & 0xffff));
            ay += w0 * bf2f((ushort_t)(xv0 >> 16))    + w1 * bf2f((ushort_t)(xv1 >> 16));
            ah += w0 * bf2f(hv0) + w1 * bf2f(hv1);
        }
        if (j < m) {
            int s0 = __shfl(sv, j); float w0 = __shfl(wv, j);
            uint_t xv0 = xb_u[(size_t)s0 * 64 + lane];
            ushort_t hv0 = hb[(size_t)s0 * 64 + lane];
            ax += w0 * bf2f((ushort_t)(xv0 & 0xffff));
            ay += w0 * bf2f((ushort_t)(xv0 >> 16));
            ah += w0 * bf2f(hv0);
        }
    }
    Txb_u[(size_t)node * 64 + lane] = (uint_t)f2bf(ax) | ((uint_t)f2bf(ay) << 16);
    Thb[(size_t)node * 64 + lane] = f2bf(ah);
}

// ---- pack weights into MFMA B-fragment layout -------------------------------
// Wp[((ct*12 + ks)*64 + lane)*8 + j] = W[k = ks*32 + (lane>>4)*8 + j][colg = ct*16 + (lane&15)]
// colg = g*64 + hd (gate-major); rows r = [Wx0(128) | Wh0(64) | Wx1(128) | Wh1(64)]
__global__ void pack_w_kernel(const float* __restrict__ Wx, const float* __restrict__ Wh,
                              ushort_t* __restrict__ Wp) {
    int idx = blockIdx.x * blockDim.x + threadIdx.x;
    if (idx >= 384 * 256) return;
    int j = idx & 7;
    int tmp = idx >> 3;
    int lane = tmp & 63;
    int tmp2 = tmp >> 6;
    int ks = tmp2 % 12;
    int ct = tmp2 / 12;
    int k = ks * 32 + (lane >> 4) * 8 + j;
    int colg = ct * 16 + (lane & 15);
    int g = colg >> 6, hd = colg & 63;
    float v;
    if (k < 128)      v = Wx[((g * 2 + 0) * 128 + k) * 64 + hd];
    else if (k < 192) v = Wh[((g * 2 + 0) * 64 + (k - 128)) * 64 + hd];
    else if (k < 320) v = Wx[((g * 2 + 1) * 128 + (k - 192)) * 64 + hd];
    else              v = Wh[((g * 2 + 1) * 64 + (k - 320)) * 64 + hd];
    Wp[idx] = f2bf(v);
}

// ---- fused MFMA GEMM (N x 384 @ 384 x 256) + LSTM gates + head --------------
// wave computes 32 rows x 256 cols (2 row-tiles x 16 col-tiles of 16x16x32 bf16)
// C layout: col = ct*16 + (lane&15), row = (lane>>4)*4 + reg
// gate-major cols: g = ct>>2, hd = (ct&3)*16 + (lane&15) -> lane owns all 4 gates
__global__ __launch_bounds__(256) void fused_mfma(
    const ushort_t* __restrict__ xb, const ushort_t* __restrict__ hb,
    const ushort_t* __restrict__ Txb, const ushort_t* __restrict__ Thb,
    const float* __restrict__ c_in, const ushort_t* __restrict__ Wp,
    const float* __restrict__ bx, const float* __restrict__ bh,
    const float* __restrict__ wc, const float* __restrict__ bg,
    const float* __restrict__ Whead, const float* __restrict__ bhead,
    float* __restrict__ out, int N) {
    int lane = threadIdx.x & 63;
    int wave = threadIdx.x >> 6;
    int quad = lane >> 4, m = lane & 15;
    int wt = blockIdx.x * 4 + wave;   // 32-row tile index
    int row0 = wt * 32;

    int ar0 = row0 + m;      if (ar0 >= N) ar0 = N - 1;
    int ar1 = row0 + 16 + m; if (ar1 >= N) ar1 = N - 1;

    f32x4 acc[2][16];
#pragma unroll
    for (int ct = 0; ct < 16; ++ct) {
        int g = ct >> 2, hd = (ct & 3) * 16 + m;
        float b = bx[g * 64 + hd] + bh[g * 64 + hd];
        f32x4 bb = {b, b, b, b};
        acc[0][ct] = bb;
        acc[1][ct] = bb;
    }

    const short8* Wp8 = (const short8*)Wp;
    int ko = quad * 8;

#pragma unroll
    for (int ks = 0; ks < 12; ++ks) {
        const ushort_t *a0, *a1;
        if (ks < 4) {
            a0 = xb + (size_t)ar0 * 128 + ks * 32 + ko;
            a1 = xb + (size_t)ar1 * 128 + ks * 32 + ko;
        } else if (ks < 6) {
            a0 = hb + (size_t)ar0 * 64 + (ks - 4) * 32 + ko;
            a1 = hb + (size_t)ar1 * 64 + (ks - 4) * 32 + ko;
        } else if (ks < 10) {
            a0 = Txb + (size_t)ar0 * 128 + (ks - 6) * 32 + ko;
            a1 = Txb + (size_t)ar1 * 128 + (ks - 6) * 32 + ko;
        } else {
            a0 = Thb + (size_t)ar0 * 64 + (ks - 10) * 32 + ko;
            a1 = Thb + (size_t)ar1 * 64 + (ks - 10) * 32 + ko;
        }
        short8 af0 = *(const short8*)a0;
        short8 af1 = *(const short8*)a1;
#pragma unroll
        for (int ct = 0; ct < 16; ++ct) {
            short8 bf = Wp8[(ct * 12 + ks) * 64 + lane];
            acc[0][ct] = __builtin_amdgcn_mfma_f32_16x16x32_bf16(af0, bf, acc[0][ct], 0, 0, 0);
            acc[1][ct] = __builtin_amdgcn_mfma_f32_16x16x32_bf16(af1, bf, acc[1][ct], 0, 0, 0);
        }
    }

    float hp0[4] = {0.f, 0.f, 0.f, 0.f};
    float hp1[4] = {0.f, 0.f, 0.f, 0.f};
    float bhv = bhead[0];

#pragma unroll
    for (int rt = 0; rt < 2; ++rt) {
#pragma unroll
        for (int hs = 0; hs < 4; ++hs) {
            int hd = hs * 16 + m;
            float wc0 = wc[hd], wc1 = wc[64 + hd], wc2 = wc[128 + hd];
            float bg0 = bg[hd], bg1 = bg[64 + hd], bg2 = bg[128 + hd], bg3 = bg[192 + hd];
            float wh = Whead[hd];
#pragma unroll
            for (int reg = 0; reg < 4; ++reg) {
                int n = row0 + rt * 16 + quad * 4 + reg;
                if (n < N) {
                    float c_old = c_in[(size_t)n * 64 + hd];
                    float zi = acc[rt][0 * 4 + hs][reg];
                    float zf = acc[rt][1 * 4 + hs][reg];
                    float zg = acc[rt][2 * 4 + hs][reg];
                    float zo = acc[rt][3 * 4 + hs][reg];
                    float ii = fsig(zi + wc0 * c_old + bg0);
                    float ff = fsig(zf + wc1 * c_old + bg1);
                    float gg = ftanh(zg + bg2);
                    float cn = ff * c_old + ii * gg;
                    float oo = fsig(zo + wc2 * cn + bg3);
                    float hn = oo * ftanh(cn);
                    out[N + (size_t)n * 64 + hd] = hn;
                    out[N + (size_t)N * 64 + (size_t)n * 64 + hd] = cn;
                    float lr = hn > 0.f ? hn : NEG_SLOPE * hn;
                    if (rt == 0) hp0[reg] += lr * wh;
                    else         hp1[reg] += lr * wh;
                }
            }
        }
    }
#pragma unroll
    for (int reg = 0; reg < 4; ++reg) {
        float v0 = hp0[reg], v1 = hp1[reg];
#pragma unroll
        for (int mask = 1; mask < 16; mask <<= 1) {
            v0 += __shfl_xor(v0, mask);
            v1 += __shfl_xor(v1, mask);
        }
        if (m == 0) {
            int n0_ = row0 + quad * 4 + reg;
            int n1_ = row0 + 16 + quad * 4 + reg;
            if (n0_ < N) out[n0_] = v0 + bhv;
            if (n1_ < N) out[n1_] = v1 + bhv;
        }
    }
}

extern "C" void kernel_launch(void* const* d_in, const int* in_sizes, int n_in,
                              void* d_out, int out_size, void* d_ws, size_t ws_size,
                              hipStream_t stream) {
    const float* x = (const float*)d_in[0];
    const int* ei = (const int*)d_in[1];
    const float* ew = (const float*)d_in[2];
    const float* h = (const float*)d_in[3];
    const float* c = (const float*)d_in[4];
    const float* Wx = (const float*)d_in[5];
    const float* bx = (const float*)d_in[6];
    const float* Wh = (const float*)d_in[7];
    const float* bh = (const float*)d_in[8];
    const float* wc = (const float*)d_in[9];
    const float* bg = (const float*)d_in[10];
    const float* Whead = (const float*)d_in[11];
    const float* bhead = (const float*)d_in[12];

    int N = in_sizes[0] / IN_DIM;  // 50000
    int E = in_sizes[1] / 2;       // 800000
    const int* src = ei;
    const int* dst = ei + E;

    char* wp = (char*)d_ws;
    auto alloc = [&](size_t bytes) {
        char* p = wp;
        wp += (bytes + 255) & ~(size_t)255;
        return p;
    };
    float* deg = (float*)alloc((size_t)3 * N * 4);  // deg | cnt | fill contiguous for memset
    int* cnt = (int*)(deg + N);
    int* fill = cnt + N;
    float* dinv = (float*)alloc((size_t)N * 4);
    int* rowptr = (int*)alloc((size_t)(N + 2) * 4);
    int* bsum = (int*)alloc(64 * 4);
    int* esrc = (int*)alloc((size_t)E * 4);
    float* enrm = (float*)alloc((size_t)E * 4);
    ushort_t* xb = (ushort_t*)alloc((size_t)N * 128 * 2);
    ushort_t* hb = (ushort_t*)alloc((size_t)N * 64 * 2);
    ushort_t* Txb = (ushort_t*)alloc((size_t)N * 128 * 2);
    ushort_t* Thb = (ushort_t*)alloc((size_t)N * 64 * 2);
    ushort_t* Wp = (ushort_t*)alloc((size_t)384 * 256 * 2);

    hipMemsetAsync(deg, 0, (size_t)3 * N * sizeof(float), stream);

    int nScan = N + 1;
    int nBlocksScan = (nScan + 1023) / 1024;

    cvt_kernel<<<(N * 96 + 255) / 256, 256, 0, stream>>>(x, h, (uint_t*)xb, (uint_t*)hb, N);
    deg_hist_kernel<<<(E + 255) / 256, 256, 0, stream>>>(src, dst, ew, deg, cnt, E);
    dinv_kernel<<<(N + 255) / 256, 256, 0, stream>>>(deg, dinv, N);
    scan1_kernel<<<nBlocksScan, 256, 0, stream>>>(cnt, rowptr, bsum, nScan, N);
    scan2_kernel<<<1, 64, 0, stream>>>(bsum, nBlocksScan);
    scan3_kernel<<<(nScan + 255) / 256, 256, 0, stream>>>(rowptr, bsum, nScan);
    fill_kernel<<<(E + 255) / 256, 256, 0, stream>>>(src, dst, ew, dinv, rowptr, fill, esrc, enrm, E);
    pack_w_kernel<<<(384 * 256 + 255) / 256, 256, 0, stream>>>(Wx, Wh, Wp);
    gather_kernel<<<(N + 3) / 4, 256, 0, stream>>>(rowptr, esrc, enrm, (const uint_t*)xb, hb,
                                                   (uint_t*)Txb, Thb, N);
    fused_mfma<<<(N + 127) / 128, 256, 0, stream>>>(xb, hb, Txb, Thb, c, Wp, bx, bh, wc, bg,
                                                    Whead, bhead, (float*)d_out, N);
}

// Round 4
// 348.438 us; speedup vs baseline: 6.6880x; 1.1898x over previous
//
#include <hip/hip_runtime.h>
#include <hip/hip_bf16.h>

#define IN_DIM 128
#define HID 64
#define NEG_SLOPE 0.01f

typedef __attribute__((ext_vector_type(8))) short short8;
typedef __attribute__((ext_vector_type(4))) short short4v;
typedef __attribute__((ext_vector_type(4))) float f32x4;
typedef unsigned short ushort_t;
typedef unsigned int uint_t;

__device__ __forceinline__ float fsig(float x) { return 1.f / (1.f + __expf(-x)); }
__device__ __forceinline__ float ftanh(float x) { return 1.f - 2.f / (__expf(2.f * x) + 1.f); }

__device__ __forceinline__ ushort_t f2bf(float f) {
    uint_t u = __float_as_uint(f);
    uint_t r = u + 0x7fffu + ((u >> 16) & 1u);  // round-to-nearest-even
    return (ushort_t)(r >> 16);
}
__device__ __forceinline__ float bf2f(ushort_t s) { return __uint_as_float(((uint_t)s) << 16); }
__device__ __forceinline__ float bf2f_s(short s) { return bf2f((ushort_t)s); }

// ---- convert x,h to bf16 ----------------------------------------------------
__global__ void cvt_kernel(const float* __restrict__ x, const float* __restrict__ h,
                           uint_t* __restrict__ xb_u, uint_t* __restrict__ hb_u, int N) {
    int i = blockIdx.x * blockDim.x + threadIdx.x;
    int nx = N * 64;
    if (i < nx) {
        float2 v = ((const float2*)x)[i];
        xb_u[i] = (uint_t)f2bf(v.x) | ((uint_t)f2bf(v.y) << 16);
    } else if (i < N * 96) {
        int j = i - nx;
        float2 v = ((const float2*)h)[j];
        hb_u[j] = (uint_t)f2bf(v.x) | ((uint_t)f2bf(v.y) << 16);
    }
}

// ---- degree (by src, float) + histogram (by dst, int) -----------------------
__global__ void deg_hist_kernel(const int* __restrict__ src, const int* __restrict__ dst,
                                const float* __restrict__ ew, float* __restrict__ deg,
                                int* __restrict__ cnt, int E) {
    int e = blockIdx.x * blockDim.x + threadIdx.x;
    if (e < E) {
        atomicAdd(&deg[src[e]], ew[e]);
        atomicAdd(&cnt[dst[e]], 1);
    }
}

__global__ void dinv_kernel(const float* __restrict__ deg, float* __restrict__ dinv, int N) {
    int n = blockIdx.x * blockDim.x + threadIdx.x;
    if (n < N) {
        float d = deg[n];
        dinv[n] = d > 0.f ? rsqrtf(d) : 0.f;
    }
}

// ---- 3-kernel exclusive scan over cnt[0..N-1] (scan length N+1) -------------
__global__ __launch_bounds__(256) void scan1_kernel(const int* __restrict__ cnt,
                                                    int* __restrict__ rowptr,
                                                    int* __restrict__ bsum, int n, int N) {
    __shared__ int sdata[256];
    int b = blockIdx.x, t = threadIdx.x;
    int base = b * 1024 + t * 4;
    int v[4];
    int tsum = 0;
#pragma unroll
    for (int j = 0; j < 4; ++j) {
        int idx = base + j;
        v[j] = (idx < N) ? cnt[idx] : 0;
        tsum += v[j];
    }
    sdata[t] = tsum;
    __syncthreads();
    for (int off = 1; off < 256; off <<= 1) {
        int tmp = (t >= off) ? sdata[t - off] : 0;
        __syncthreads();
        sdata[t] += tmp;
        __syncthreads();
    }
    if (t == 255) bsum[b] = sdata[255];
    int run = sdata[t] - tsum;
#pragma unroll
    for (int j = 0; j < 4; ++j) {
        int idx = base + j;
        if (idx < n) rowptr[idx] = run;
        run += v[j];
    }
}

__global__ void scan2_kernel(int* __restrict__ bsum, int nb) {
    if (threadIdx.x == 0 && blockIdx.x == 0) {
        int run = 0;
        for (int i = 0; i < nb; ++i) {
            int v = bsum[i];
            bsum[i] = run;
            run += v;
        }
    }
}

__global__ void scan3_kernel(int* __restrict__ rowptr, const int* __restrict__ bsum, int n) {
    int i = blockIdx.x * blockDim.x + threadIdx.x;
    if (i < n) rowptr[i] += bsum[i >> 10];
}

// ---- fill CSR: esrc/enrm sorted by dst --------------------------------------
__global__ void fill_kernel(const int* __restrict__ src, const int* __restrict__ dst,
                            const float* __restrict__ ew, const float* __restrict__ dinv,
                            const int* __restrict__ rowptr, int* __restrict__ fill,
                            int* __restrict__ esrc, float* __restrict__ enrm, int E) {
    int e = blockIdx.x * blockDim.x + threadIdx.x;
    if (e < E) {
        int d = dst[e];
        int s = src[e];
        int pos = rowptr[d] + atomicAdd(&fill[d], 1);
        esrc[pos] = s;
        enrm[pos] = -dinv[s] * ew[e] * dinv[d];
    }
}

// ---- gather v2: 4 nodes per wave, 16 lanes per node -------------------------
// lane l16 covers x dims [l16*8, l16*8+8) and h dims [l16*4, l16*4+4)
__global__ __launch_bounds__(256) void gather_kernel(const int* __restrict__ rowptr,
                                                     const int* __restrict__ esrc,
                                                     const float* __restrict__ enrm,
                                                     const ushort_t* __restrict__ xb,
                                                     const ushort_t* __restrict__ hb,
                                                     ushort_t* __restrict__ Txb,
                                                     ushort_t* __restrict__ Thb, int N) {
    int lane = threadIdx.x & 63;
    int wave = threadIdx.x >> 6;
    int grp = lane >> 4, l16 = lane & 15;
    int node = blockIdx.x * 16 + wave * 4 + grp;
    bool valid = node < N;
    int p = 0, end = 0;
    if (valid) { p = rowptr[node]; end = rowptr[node + 1]; }

    float ax[8] = {0.f, 0.f, 0.f, 0.f, 0.f, 0.f, 0.f, 0.f};
    float ah[4] = {0.f, 0.f, 0.f, 0.f};

    for (int base = p; base < end; base += 16) {
        int idx = base + l16;
        int sv = (idx < end) ? esrc[idx] : 0;
        float wv = (idx < end) ? enrm[idx] : 0.f;
        int mcount = end - base; if (mcount > 16) mcount = 16;
        int sl0 = grp * 16;
        int j = 0;
        for (; j + 4 <= mcount; j += 4) {
            int s0 = __shfl(sv, sl0 + j + 0), s1 = __shfl(sv, sl0 + j + 1);
            int s2 = __shfl(sv, sl0 + j + 2), s3 = __shfl(sv, sl0 + j + 3);
            float w0 = __shfl(wv, sl0 + j + 0), w1 = __shfl(wv, sl0 + j + 1);
            float w2 = __shfl(wv, sl0 + j + 2), w3 = __shfl(wv, sl0 + j + 3);
            short8 xv0 = *(const short8*)(xb + (size_t)s0 * 128 + l16 * 8);
            short8 xv1 = *(const short8*)(xb + (size_t)s1 * 128 + l16 * 8);
            short8 xv2 = *(const short8*)(xb + (size_t)s2 * 128 + l16 * 8);
            short8 xv3 = *(const short8*)(xb + (size_t)s3 * 128 + l16 * 8);
            short4v hv0 = *(const short4v*)(hb + (size_t)s0 * 64 + l16 * 4);
            short4v hv1 = *(const short4v*)(hb + (size_t)s1 * 64 + l16 * 4);
            short4v hv2 = *(const short4v*)(hb + (size_t)s2 * 64 + l16 * 4);
            short4v hv3 = *(const short4v*)(hb + (size_t)s3 * 64 + l16 * 4);
#pragma unroll
            for (int i = 0; i < 8; ++i)
                ax[i] += w0 * bf2f_s(xv0[i]) + w1 * bf2f_s(xv1[i])
                       + w2 * bf2f_s(xv2[i]) + w3 * bf2f_s(xv3[i]);
#pragma unroll
            for (int i = 0; i < 4; ++i)
                ah[i] += w0 * bf2f_s(hv0[i]) + w1 * bf2f_s(hv1[i])
                       + w2 * bf2f_s(hv2[i]) + w3 * bf2f_s(hv3[i]);
        }
        for (; j < mcount; ++j) {
            int s0 = __shfl(sv, sl0 + j);
            float w0 = __shfl(wv, sl0 + j);
            short8 xv0 = *(const short8*)(xb + (size_t)s0 * 128 + l16 * 8);
            short4v hv0 = *(const short4v*)(hb + (size_t)s0 * 64 + l16 * 4);
#pragma unroll
            for (int i = 0; i < 8; ++i) ax[i] += w0 * bf2f_s(xv0[i]);
#pragma unroll
            for (int i = 0; i < 4; ++i) ah[i] += w0 * bf2f_s(hv0[i]);
        }
    }

    if (valid) {
        short8 tx;
#pragma unroll
        for (int i = 0; i < 8; ++i) tx[i] = (short)f2bf(ax[i]);
        *(short8*)(Txb + (size_t)node * 128 + l16 * 8) = tx;
        short4v th;
#pragma unroll
        for (int i = 0; i < 4; ++i) th[i] = (short)f2bf(ah[i]);
        *(short4v*)(Thb + (size_t)node * 64 + l16 * 4) = th;
    }
}

// ---- pack weights into MFMA B-fragment layout, [ks][ct] contiguous ----------
// Wp[((ks*16 + ct)*64 + lane)*8 + j] = W[k = ks*32 + (lane>>4)*8 + j][colg = ct*16 + (lane&15)]
// colg = g*64 + hd (gate-major); rows k = [Wx0(128) | Wh0(64) | Wx1(128) | Wh1(64)]
__global__ void pack_w_kernel(const float* __restrict__ Wx, const float* __restrict__ Wh,
                              ushort_t* __restrict__ Wp) {
    int idx = blockIdx.x * blockDim.x + threadIdx.x;
    if (idx >= 384 * 256) return;
    int j = idx & 7;
    int tmp = idx >> 3;
    int lane = tmp & 63;
    int t2 = tmp >> 6;
    int ct = t2 & 15;
    int ks = t2 >> 4;
    int k = ks * 32 + (lane >> 4) * 8 + j;
    int colg = ct * 16 + (lane & 15);
    int g = colg >> 6, hd = colg & 63;
    float v;
    if (k < 128)      v = Wx[((g * 2 + 0) * 128 + k) * 64 + hd];
    else if (k < 192) v = Wh[((g * 2 + 0) * 64 + (k - 128)) * 64 + hd];
    else if (k < 320) v = Wx[((g * 2 + 1) * 128 + (k - 192)) * 64 + hd];
    else              v = Wh[((g * 2 + 1) * 64 + (k - 320)) * 64 + hd];
    Wp[idx] = f2bf(v);
}

// ---- fused MFMA GEMM (N x 384 @ 384 x 256) + LSTM gates + head --------------
// wave computes 16 rows x 256 cols (16 col-tiles of 16x16x32 bf16), acc = 64 VGPRs
// C layout: col = ct*16 + (lane&15), row = (lane>>4)*4 + reg
__global__ __launch_bounds__(256, 4) void fused_mfma(
    const ushort_t* __restrict__ xb, const ushort_t* __restrict__ hb,
    const ushort_t* __restrict__ Txb, const ushort_t* __restrict__ Thb,
    const float* __restrict__ c_in, const ushort_t* __restrict__ Wp,
    const float* __restrict__ bx, const float* __restrict__ bh,
    const float* __restrict__ wc, const float* __restrict__ bg,
    const float* __restrict__ Whead, const float* __restrict__ bhead,
    float* __restrict__ out, int N) {
    int lane = threadIdx.x & 63;
    int wave = threadIdx.x >> 6;
    int quad = lane >> 4, m = lane & 15;
    int wt = blockIdx.x * 4 + wave;   // 16-row tile index
    int row0 = wt * 16;

    int ar = row0 + m; if (ar >= N) ar = N - 1;

    f32x4 acc[16];
#pragma unroll
    for (int ct = 0; ct < 16; ++ct) {
        int g = ct >> 2, hd = (ct & 3) * 16 + m;
        float b = bx[g * 64 + hd] + bh[g * 64 + hd];
        f32x4 bb = {b, b, b, b};
        acc[ct] = bb;
    }

    const short8* Wp8 = (const short8*)Wp;
    int ko = quad * 8;

#pragma unroll
    for (int ks = 0; ks < 12; ++ks) {
        const ushort_t* a;
        if (ks < 4)       a = xb  + (size_t)ar * 128 + ks * 32 + ko;
        else if (ks < 6)  a = hb  + (size_t)ar * 64 + (ks - 4) * 32 + ko;
        else if (ks < 10) a = Txb + (size_t)ar * 128 + (ks - 6) * 32 + ko;
        else              a = Thb + (size_t)ar * 64 + (ks - 10) * 32 + ko;
        short8 af = *(const short8*)a;
#pragma unroll
        for (int ct = 0; ct < 16; ++ct) {
            short8 bf = Wp8[(ks * 16 + ct) * 64 + lane];
            acc[ct] = __builtin_amdgcn_mfma_f32_16x16x32_bf16(af, bf, acc[ct], 0, 0, 0);
        }
    }

    float hp[4] = {0.f, 0.f, 0.f, 0.f};
    float bhv = bhead[0];

#pragma unroll
    for (int hs = 0; hs < 4; ++hs) {
        int hd = hs * 16 + m;
        float wc0 = wc[hd], wc1 = wc[64 + hd], wc2 = wc[128 + hd];
        float bg0 = bg[hd], bg1 = bg[64 + hd], bg2 = bg[128 + hd], bg3 = bg[192 + hd];
        float wh = Whead[hd];
#pragma unroll
        for (int reg = 0; reg < 4; ++reg) {
            int n = row0 + quad * 4 + reg;
            if (n < N) {
                float c_old = c_in[(size_t)n * 64 + hd];
                float zi = acc[0 * 4 + hs][reg];
                float zf = acc[1 * 4 + hs][reg];
                float zg = acc[2 * 4 + hs][reg];
                float zo = acc[3 * 4 + hs][reg];
                float ii = fsig(zi + wc0 * c_old + bg0);
                float ff = fsig(zf + wc1 * c_old + bg1);
                float gg = ftanh(zg + bg2);
                float cn = ff * c_old + ii * gg;
                float oo = fsig(zo + wc2 * cn + bg3);
                float hn = oo * ftanh(cn);
                out[N + (size_t)n * 64 + hd] = hn;
                out[N + (size_t)N * 64 + (size_t)n * 64 + hd] = cn;
                float lr = hn > 0.f ? hn : NEG_SLOPE * hn;
                hp[reg] += lr * wh;
            }
        }
    }
#pragma unroll
    for (int reg = 0; reg < 4; ++reg) {
        float v0 = hp[reg];
#pragma unroll
        for (int mask = 1; mask < 16; mask <<= 1) v0 += __shfl_xor(v0, mask);
        if (m == 0) {
            int n0_ = row0 + quad * 4 + reg;
            if (n0_ < N) out[n0_] = v0 + bhv;
        }
    }
}

extern "C" void kernel_launch(void* const* d_in, const int* in_sizes, int n_in,
                              void* d_out, int out_size, void* d_ws, size_t ws_size,
                              hipStream_t stream) {
    const float* x = (const float*)d_in[0];
    const int* ei = (const int*)d_in[1];
    const float* ew = (const float*)d_in[2];
    const float* h = (const float*)d_in[3];
    const float* c = (const float*)d_in[4];
    const float* Wx = (const float*)d_in[5];
    const float* bx = (const float*)d_in[6];
    const float* Wh = (const float*)d_in[7];
    const float* bh = (const float*)d_in[8];
    const float* wc = (const float*)d_in[9];
    const float* bg = (const float*)d_in[10];
    const float* Whead = (const float*)d_in[11];
    const float* bhead = (const float*)d_in[12];

    int N = in_sizes[0] / IN_DIM;  // 50000
    int E = in_sizes[1] / 2;       // 800000
    const int* src = ei;
    const int* dst = ei + E;

    char* wp = (char*)d_ws;
    auto alloc = [&](size_t bytes) {
        char* p = wp;
        wp += (bytes + 255) & ~(size_t)255;
        return p;
    };
    float* deg = (float*)alloc((size_t)3 * N * 4);  // deg | cnt | fill contiguous for memset
    int* cnt = (int*)(deg + N);
    int* fill = cnt + N;
    float* dinv = (float*)alloc((size_t)N * 4);
    int* rowptr = (int*)alloc((size_t)(N + 2) * 4);
    int* bsum = (int*)alloc(64 * 4);
    int* esrc = (int*)alloc((size_t)E * 4);
    float* enrm = (float*)alloc((size_t)E * 4);
    ushort_t* xb = (ushort_t*)alloc((size_t)N * 128 * 2);
    ushort_t* hb = (ushort_t*)alloc((size_t)N * 64 * 2);
    ushort_t* Txb = (ushort_t*)alloc((size_t)N * 128 * 2);
    ushort_t* Thb = (ushort_t*)alloc((size_t)N * 64 * 2);
    ushort_t* Wp = (ushort_t*)alloc((size_t)384 * 256 * 2);

    hipMemsetAsync(deg, 0, (size_t)3 * N * sizeof(float), stream);

    int nScan = N + 1;
    int nBlocksScan = (nScan + 1023) / 1024;

    cvt_kernel<<<(N * 96 + 255) / 256, 256, 0, stream>>>(x, h, (uint_t*)xb, (uint_t*)hb, N);
    deg_hist_kernel<<<(E + 255) / 256, 256, 0, stream>>>(src, dst, ew, deg, cnt, E);
    dinv_kernel<<<(N + 255) / 256, 256, 0, stream>>>(deg, dinv, N);
    scan1_kernel<<<nBlocksScan, 256, 0, stream>>>(cnt, rowptr, bsum, nScan, N);
    scan2_kernel<<<1, 64, 0, stream>>>(bsum, nBlocksScan);
    scan3_kernel<<<(nScan + 255) / 256, 256, 0, stream>>>(rowptr, bsum, nScan);
    fill_kernel<<<(E + 255) / 256, 256, 0, stream>>>(src, dst, ew, dinv, rowptr, fill, esrc, enrm, E);
    pack_w_kernel<<<(384 * 256 + 255) / 256, 256, 0, stream>>>(Wx, Wh, Wp);
    gather_kernel<<<(N + 15) / 16, 256, 0, stream>>>(rowptr, esrc, enrm, xb, hb, Txb, Thb, N);
    fused_mfma<<<(N + 63) / 64, 256, 0, stream>>>(xb, hb, Txb, Thb, c, Wp, bx, bh, wc, bg,
                                                  Whead, bhead, (float*)d_out, N);
}

// Round 5
// 314.166 us; speedup vs baseline: 7.4176x; 1.1091x over previous
//
#include <hip/hip_runtime.h>
#include <hip/hip_bf16.h>

#define IN_DIM 128
#define HID 64
#define NEG_SLOPE 0.01f

typedef __attribute__((ext_vector_type(8))) short short8;
typedef __attribute__((ext_vector_type(4))) short short4v;
typedef __attribute__((ext_vector_type(4))) float f32x4;
typedef unsigned short ushort_t;
typedef unsigned int uint_t;

__device__ __forceinline__ float fsig(float x) { return 1.f / (1.f + __expf(-x)); }
__device__ __forceinline__ float ftanh(float x) { return 1.f - 2.f / (__expf(2.f * x) + 1.f); }

__device__ __forceinline__ ushort_t f2bf(float f) {
    uint_t u = __float_as_uint(f);
    uint_t r = u + 0x7fffu + ((u >> 16) & 1u);  // round-to-nearest-even
    return (ushort_t)(r >> 16);
}
__device__ __forceinline__ float bf2f(ushort_t s) { return __uint_as_float(((uint_t)s) << 16); }
__device__ __forceinline__ float bf2f_s(short s) { return bf2f((ushort_t)s); }

// ---- convert x,h to bf16 ----------------------------------------------------
__global__ void cvt_kernel(const float* __restrict__ x, const float* __restrict__ h,
                           uint_t* __restrict__ xb_u, uint_t* __restrict__ hb_u, int N) {
    int i = blockIdx.x * blockDim.x + threadIdx.x;
    int nx = N * 64;
    if (i < nx) {
        float2 v = ((const float2*)x)[i];
        xb_u[i] = (uint_t)f2bf(v.x) | ((uint_t)f2bf(v.y) << 16);
    } else if (i < N * 96) {
        int j = i - nx;
        float2 v = ((const float2*)h)[j];
        hb_u[j] = (uint_t)f2bf(v.x) | ((uint_t)f2bf(v.y) << 16);
    }
}

// ---- degree (by src) + histogram (by dst) + per-edge rank -------------------
__global__ void deg_hist_kernel(const int* __restrict__ src, const int* __restrict__ dst,
                                const float* __restrict__ ew, float* __restrict__ deg,
                                int* __restrict__ cnt, int* __restrict__ rank, int E) {
    int e = blockIdx.x * blockDim.x + threadIdx.x;
    if (e < E) {
        atomicAdd(&deg[src[e]], ew[e]);
        rank[e] = atomicAdd(&cnt[dst[e]], 1);   // rank within dst bucket (free w/ same atomic)
    }
}

// ---- 3-kernel exclusive scan over cnt[0..N-1] (scan length N+1) -------------
__global__ __launch_bounds__(256) void scan1_kernel(const int* __restrict__ cnt,
                                                    int* __restrict__ rowptr,
                                                    int* __restrict__ bsum, int n, int N) {
    __shared__ int sdata[256];
    int b = blockIdx.x, t = threadIdx.x;
    int base = b * 1024 + t * 4;
    int v[4];
    int tsum = 0;
#pragma unroll
    for (int j = 0; j < 4; ++j) {
        int idx = base + j;
        v[j] = (idx < N) ? cnt[idx] : 0;
        tsum += v[j];
    }
    sdata[t] = tsum;
    __syncthreads();
    for (int off = 1; off < 256; off <<= 1) {
        int tmp = (t >= off) ? sdata[t - off] : 0;
        __syncthreads();
        sdata[t] += tmp;
        __syncthreads();
    }
    if (t == 255) bsum[b] = sdata[255];
    int run = sdata[t] - tsum;
#pragma unroll
    for (int j = 0; j < 4; ++j) {
        int idx = base + j;
        if (idx < n) rowptr[idx] = run;
        run += v[j];
    }
}

// scan2: single-wave shfl scan of block sums (nb <= 64)
__global__ void scan2_kernel(int* __restrict__ bsum, int nb) {
    int l = threadIdx.x;
    int orig = (l < nb) ? bsum[l] : 0;
    int v = orig;
#pragma unroll
    for (int off = 1; off < 64; off <<= 1) {
        int t = __shfl_up(v, off);
        if (l >= off) v += t;
    }
    if (l < nb) bsum[l] = v - orig;  // exclusive
}

__global__ void scan3_kernel(int* __restrict__ rowptr, const int* __restrict__ bsum, int n) {
    int i = blockIdx.x * blockDim.x + threadIdx.x;
    if (i < n) rowptr[i] += bsum[i >> 10];
}

// ---- fill CSR (atomic-free): eprm[pos] = {src, nrm} -------------------------
__global__ void fill_kernel(const int* __restrict__ src, const int* __restrict__ dst,
                            const float* __restrict__ ew, const float* __restrict__ deg,
                            const int* __restrict__ rowptr, const int* __restrict__ rank,
                            int2* __restrict__ eprm, int E) {
    int e = blockIdx.x * blockDim.x + threadIdx.x;
    if (e < E) {
        int d = dst[e];
        int s = src[e];
        float ds = deg[s], dd = deg[d];
        float dis = ds > 0.f ? rsqrtf(ds) : 0.f;
        float did = dd > 0.f ? rsqrtf(dd) : 0.f;
        float nrm = -dis * ew[e] * did;
        int pos = rowptr[d] + rank[e];
        eprm[pos] = make_int2(s, __float_as_int(nrm));
    }
}

// ---- gather: 4 nodes per wave, 16 lanes per node ----------------------------
__global__ __launch_bounds__(256) void gather_kernel(const int* __restrict__ rowptr,
                                                     const int2* __restrict__ eprm,
                                                     const ushort_t* __restrict__ xb,
                                                     const ushort_t* __restrict__ hb,
                                                     ushort_t* __restrict__ Txb,
                                                     ushort_t* __restrict__ Thb, int N) {
    int lane = threadIdx.x & 63;
    int wave = threadIdx.x >> 6;
    int grp = lane >> 4, l16 = lane & 15;
    int node = blockIdx.x * 16 + wave * 4 + grp;
    bool valid = node < N;
    int p = 0, end = 0;
    if (valid) { p = rowptr[node]; end = rowptr[node + 1]; }

    float ax[8] = {0.f, 0.f, 0.f, 0.f, 0.f, 0.f, 0.f, 0.f};
    float ah[4] = {0.f, 0.f, 0.f, 0.f};

    for (int base = p; base < end; base += 16) {
        int idx = base + l16;
        int2 pr = (idx < end) ? eprm[idx] : make_int2(0, 0);
        int sv = pr.x;
        float wv = __int_as_float(pr.y);
        int mcount = end - base; if (mcount > 16) mcount = 16;
        int sl0 = grp * 16;
        int j = 0;
        for (; j + 4 <= mcount; j += 4) {
            int s0 = __shfl(sv, sl0 + j + 0), s1 = __shfl(sv, sl0 + j + 1);
            int s2 = __shfl(sv, sl0 + j + 2), s3 = __shfl(sv, sl0 + j + 3);
            float w0 = __shfl(wv, sl0 + j + 0), w1 = __shfl(wv, sl0 + j + 1);
            float w2 = __shfl(wv, sl0 + j + 2), w3 = __shfl(wv, sl0 + j + 3);
            short8 xv0 = *(const short8*)(xb + (size_t)s0 * 128 + l16 * 8);
            short8 xv1 = *(const short8*)(xb + (size_t)s1 * 128 + l16 * 8);
            short8 xv2 = *(const short8*)(xb + (size_t)s2 * 128 + l16 * 8);
            short8 xv3 = *(const short8*)(xb + (size_t)s3 * 128 + l16 * 8);
            short4v hv0 = *(const short4v*)(hb + (size_t)s0 * 64 + l16 * 4);
            short4v hv1 = *(const short4v*)(hb + (size_t)s1 * 64 + l16 * 4);
            short4v hv2 = *(const short4v*)(hb + (size_t)s2 * 64 + l16 * 4);
            short4v hv3 = *(const short4v*)(hb + (size_t)s3 * 64 + l16 * 4);
#pragma unroll
            for (int i = 0; i < 8; ++i)
                ax[i] += w0 * bf2f_s(xv0[i]) + w1 * bf2f_s(xv1[i])
                       + w2 * bf2f_s(xv2[i]) + w3 * bf2f_s(xv3[i]);
#pragma unroll
            for (int i = 0; i < 4; ++i)
                ah[i] += w0 * bf2f_s(hv0[i]) + w1 * bf2f_s(hv1[i])
                       + w2 * bf2f_s(hv2[i]) + w3 * bf2f_s(hv3[i]);
        }
        for (; j < mcount; ++j) {
            int s0 = __shfl(sv, sl0 + j);
            float w0 = __shfl(wv, sl0 + j);
            short8 xv0 = *(const short8*)(xb + (size_t)s0 * 128 + l16 * 8);
            short4v hv0 = *(const short4v*)(hb + (size_t)s0 * 64 + l16 * 4);
#pragma unroll
            for (int i = 0; i < 8; ++i) ax[i] += w0 * bf2f_s(xv0[i]);
#pragma unroll
            for (int i = 0; i < 4; ++i) ah[i] += w0 * bf2f_s(hv0[i]);
        }
    }

    if (valid) {
        short8 tx;
#pragma unroll
        for (int i = 0; i < 8; ++i) tx[i] = (short)f2bf(ax[i]);
        *(short8*)(Txb + (size_t)node * 128 + l16 * 8) = tx;
        short4v th;
#pragma unroll
        for (int i = 0; i < 4; ++i) th[i] = (short)f2bf(ah[i]);
        *(short4v*)(Thb + (size_t)node * 64 + l16 * 4) = th;
    }
}

// ---- pack weights into MFMA B-fragment layout, [ks][ct] contiguous ----------
// Wp[((ks*16 + ct)*64 + lane)*8 + j] = W[k = ks*32 + (lane>>4)*8 + j][colg = ct*16 + (lane&15)]
__global__ void pack_w_kernel(const float* __restrict__ Wx, const float* __restrict__ Wh,
                              ushort_t* __restrict__ Wp) {
    int idx = blockIdx.x * blockDim.x + threadIdx.x;
    if (idx >= 384 * 256) return;
    int j = idx & 7;
    int tmp = idx >> 3;
    int lane = tmp & 63;
    int t2 = tmp >> 6;
    int ct = t2 & 15;
    int ks = t2 >> 4;
    int k = ks * 32 + (lane >> 4) * 8 + j;
    int colg = ct * 16 + (lane & 15);
    int g = colg >> 6, hd = colg & 63;
    float v;
    if (k < 128)      v = Wx[((g * 2 + 0) * 128 + k) * 64 + hd];
    else if (k < 192) v = Wh[((g * 2 + 0) * 64 + (k - 128)) * 64 + hd];
    else if (k < 320) v = Wx[((g * 2 + 1) * 128 + (k - 192)) * 64 + hd];
    else              v = Wh[((g * 2 + 1) * 64 + (k - 320)) * 64 + hd];
    Wp[idx] = f2bf(v);
}

// ---- fused MFMA GEMM + LSTM gates + head, LDS-shared B (double-buffered) ----
// wave computes 16 rows x 256 cols; block of 4 waves shares per-ks B tiles (16 KB)
__global__ __launch_bounds__(256, 4) void fused_mfma(
    const ushort_t* __restrict__ xb, const ushort_t* __restrict__ hb,
    const ushort_t* __restrict__ Txb, const ushort_t* __restrict__ Thb,
    const float* __restrict__ c_in, const ushort_t* __restrict__ Wp,
    const float* __restrict__ bx, const float* __restrict__ bh,
    const float* __restrict__ wc, const float* __restrict__ bg,
    const float* __restrict__ Whead, const float* __restrict__ bhead,
    float* __restrict__ out, int N) {
    __shared__ ushort_t Bs[2][8192];  // 2 x 16 KB ks-tiles
    int tid = threadIdx.x;
    int lane = tid & 63;
    int wave = tid >> 6;
    int quad = lane >> 4, m = lane & 15;
    int row0 = (blockIdx.x * 4 + wave) * 16;
    int ar = row0 + m; if (ar >= N) ar = N - 1;

    // stage ks-tile 0
    {
        const float4* gsrc = (const float4*)(Wp);
        float4* ldst = (float4*)Bs[0];
#pragma unroll
        for (int i = 0; i < 4; ++i) ldst[tid + 256 * i] = gsrc[tid + 256 * i];
    }

    f32x4 acc[16];
#pragma unroll
    for (int ct = 0; ct < 16; ++ct) {
        int g = ct >> 2, hd = (ct & 3) * 16 + m;
        float b = bx[g * 64 + hd] + bh[g * 64 + hd];
        f32x4 bb = {b, b, b, b};
        acc[ct] = bb;
    }

    int ko = quad * 8;
    __syncthreads();

#pragma unroll
    for (int ks = 0; ks < 12; ++ks) {
        int buf = ks & 1;
        float4 tmp[4];
        if (ks < 11) {
            const float4* gsrc = (const float4*)(Wp + (ks + 1) * 8192);
#pragma unroll
            for (int i = 0; i < 4; ++i) tmp[i] = gsrc[tid + 256 * i];
        }
        const ushort_t* a;
        if (ks < 4)       a = xb  + (size_t)ar * 128 + ks * 32 + ko;
        else if (ks < 6)  a = hb  + (size_t)ar * 64 + (ks - 4) * 32 + ko;
        else if (ks < 10) a = Txb + (size_t)ar * 128 + (ks - 6) * 32 + ko;
        else              a = Thb + (size_t)ar * 64 + (ks - 10) * 32 + ko;
        short8 af = *(const short8*)a;
        const short8* bsp = (const short8*)Bs[buf];
#pragma unroll
        for (int ct = 0; ct < 16; ++ct) {
            short8 bf = bsp[ct * 64 + lane];
            acc[ct] = __builtin_amdgcn_mfma_f32_16x16x32_bf16(af, bf, acc[ct], 0, 0, 0);
        }
        if (ks < 11) {
            float4* ldst = (float4*)Bs[buf ^ 1];
#pragma unroll
            for (int i = 0; i < 4; ++i) ldst[tid + 256 * i] = tmp[i];
            __syncthreads();
        }
    }

    float hp[4] = {0.f, 0.f, 0.f, 0.f};
    float bhv = bhead[0];

#pragma unroll
    for (int hs = 0; hs < 4; ++hs) {
        int hd = hs * 16 + m;
        float wc0 = wc[hd], wc1 = wc[64 + hd], wc2 = wc[128 + hd];
        float bg0 = bg[hd], bg1 = bg[64 + hd], bg2 = bg[128 + hd], bg3 = bg[192 + hd];
        float wh = Whead[hd];
#pragma unroll
        for (int reg = 0; reg < 4; ++reg) {
            int n = row0 + quad * 4 + reg;
            if (n < N) {
                float c_old = c_in[(size_t)n * 64 + hd];
                float zi = acc[0 * 4 + hs][reg];
                float zf = acc[1 * 4 + hs][reg];
                float zg = acc[2 * 4 + hs][reg];
                float zo = acc[3 * 4 + hs][reg];
                float ii = fsig(zi + wc0 * c_old + bg0);
                float ff = fsig(zf + wc1 * c_old + bg1);
                float gg = ftanh(zg + bg2);
                float cn = ff * c_old + ii * gg;
                float oo = fsig(zo + wc2 * cn + bg3);
                float hn = oo * ftanh(cn);
                out[N + (size_t)n * 64 + hd] = hn;
                out[N + (size_t)N * 64 + (size_t)n * 64 + hd] = cn;
                float lr = hn > 0.f ? hn : NEG_SLOPE * hn;
                hp[reg] += lr * wh;
            }
        }
    }
#pragma unroll
    for (int reg = 0; reg < 4; ++reg) {
        float v0 = hp[reg];
#pragma unroll
        for (int mask = 1; mask < 16; mask <<= 1) v0 += __shfl_xor(v0, mask);
        if (m == 0) {
            int n0_ = row0 + quad * 4 + reg;
            if (n0_ < N) out[n0_] = v0 + bhv;
        }
    }
}

extern "C" void kernel_launch(void* const* d_in, const int* in_sizes, int n_in,
                              void* d_out, int out_size, void* d_ws, size_t ws_size,
                              hipStream_t stream) {
    const float* x = (const float*)d_in[0];
    const int* ei = (const int*)d_in[1];
    const float* ew = (const float*)d_in[2];
    const float* h = (const float*)d_in[3];
    const float* c = (const float*)d_in[4];
    const float* Wx = (const float*)d_in[5];
    const float* bx = (const float*)d_in[6];
    const float* Wh = (const float*)d_in[7];
    const float* bh = (const float*)d_in[8];
    const float* wc = (const float*)d_in[9];
    const float* bg = (const float*)d_in[10];
    const float* Whead = (const float*)d_in[11];
    const float* bhead = (const float*)d_in[12];

    int N = in_sizes[0] / IN_DIM;  // 50000
    int E = in_sizes[1] / 2;       // 800000
    const int* src = ei;
    const int* dst = ei + E;

    char* wp = (char*)d_ws;
    auto alloc = [&](size_t bytes) {
        char* p = wp;
        wp += (bytes + 255) & ~(size_t)255;
        return p;
    };
    float* deg = (float*)alloc((size_t)2 * N * 4);  // deg | cnt contiguous for memset
    int* cnt = (int*)(deg + N);
    int* rank = (int*)alloc((size_t)E * 4);
    int* rowptr = (int*)alloc((size_t)(N + 2) * 4);
    int* bsum = (int*)alloc(64 * 4);
    int2* eprm = (int2*)alloc((size_t)E * 8);
    ushort_t* xb = (ushort_t*)alloc((size_t)N * 128 * 2);
    ushort_t* hb = (ushort_t*)alloc((size_t)N * 64 * 2);
    ushort_t* Txb = (ushort_t*)alloc((size_t)N * 128 * 2);
    ushort_t* Thb = (ushort_t*)alloc((size_t)N * 64 * 2);
    ushort_t* Wp = (ushort_t*)alloc((size_t)384 * 256 * 2);

    hipMemsetAsync(deg, 0, (size_t)2 * N * sizeof(float), stream);

    int nScan = N + 1;
    int nBlocksScan = (nScan + 1023) / 1024;

    cvt_kernel<<<(N * 96 + 255) / 256, 256, 0, stream>>>(x, h, (uint_t*)xb, (uint_t*)hb, N);
    deg_hist_kernel<<<(E + 255) / 256, 256, 0, stream>>>(src, dst, ew, deg, cnt, rank, E);
    scan1_kernel<<<nBlocksScan, 256, 0, stream>>>(cnt, rowptr, bsum, nScan, N);
    scan2_kernel<<<1, 64, 0, stream>>>(bsum, nBlocksScan);
    scan3_kernel<<<(nScan + 255) / 256, 256, 0, stream>>>(rowptr, bsum, nScan);
    fill_kernel<<<(E + 255) / 256, 256, 0, stream>>>(src, dst, ew, deg, rowptr, rank, eprm, E);
    pack_w_kernel<<<(384 * 256 + 255) / 256, 256, 0, stream>>>(Wx, Wh, Wp);
    gather_kernel<<<(N + 15) / 16, 256, 0, stream>>>(rowptr, eprm, xb, hb, Txb, Thb, N);
    fused_mfma<<<(N + 63) / 64, 256, 0, stream>>>(xb, hb, Txb, Thb, c, Wp, bx, bh, wc, bg,
                                                  Whead, bhead, (float*)d_out, N);
}

// Round 6
// 289.203 us; speedup vs baseline: 8.0579x; 1.0863x over previous
//
#include <hip/hip_runtime.h>
#include <hip/hip_bf16.h>

#define IN_DIM 128
#define HID 64
#define NEG_SLOPE 0.01f

typedef __attribute__((ext_vector_type(8))) short short8;
typedef __attribute__((ext_vector_type(4))) short short4v;
typedef __attribute__((ext_vector_type(4))) float f32x4;
typedef unsigned short ushort_t;
typedef unsigned int uint_t;

__device__ __forceinline__ float fsig(float x) { return 1.f / (1.f + __expf(-x)); }
__device__ __forceinline__ float ftanh(float x) { return 1.f - 2.f / (__expf(2.f * x) + 1.f); }

__device__ __forceinline__ ushort_t f2bf(float f) {
    uint_t u = __float_as_uint(f);
    uint_t r = u + 0x7fffu + ((u >> 16) & 1u);  // round-to-nearest-even
    return (ushort_t)(r >> 16);
}
__device__ __forceinline__ float bf2f(ushort_t s) { return __uint_as_float(((uint_t)s) << 16); }
__device__ __forceinline__ float bf2f_s(short s) { return bf2f((ushort_t)s); }

// ---- K1: deg/rank atomics + bf16 convert + weight pack (fused) --------------
// Atomic-bound threads are ~99.7% idle; the cvt/pack bandwidth work rides free.
__global__ __launch_bounds__(256) void prep_kernel(
    const int* __restrict__ src, const int* __restrict__ dst, const float* __restrict__ ew,
    const float* __restrict__ x, const float* __restrict__ h,
    const float* __restrict__ Wx, const float* __restrict__ Wh,
    float* __restrict__ deg, int* __restrict__ cnt, int* __restrict__ rank,
    uint_t* __restrict__ xb_u, uint_t* __restrict__ hb_u, ushort_t* __restrict__ Wp,
    int E, int N) {
    int tid = blockIdx.x * 256 + threadIdx.x;
    int T = gridDim.x * 256;

    if (tid < E) {
        atomicAdd(&deg[src[tid]], ew[tid]);
        rank[tid] = atomicAdd(&cnt[dst[tid]], 1);   // rank within dst bucket
    }

    // cvt: x pairs [0, N*64), h pairs [N*64, N*96)
    int ncvt = N * 96;
    int nx = N * 64;
    for (int i = tid; i < ncvt; i += T) {
        if (i < nx) {
            float2 v = ((const float2*)x)[i];
            xb_u[i] = (uint_t)f2bf(v.x) | ((uint_t)f2bf(v.y) << 16);
        } else {
            int j = i - nx;
            float2 v = ((const float2*)h)[j];
            hb_u[j] = (uint_t)f2bf(v.x) | ((uint_t)f2bf(v.y) << 16);
        }
    }

    // pack weights into MFMA B-fragment layout, [ks][ct] contiguous:
    // Wp[((ks*16+ct)*64+lane)*8+j] = W[k=ks*32+(lane>>4)*8+j][colg=ct*16+(lane&15)]
    for (int idx = tid; idx < 384 * 256; idx += T) {
        int j = idx & 7;
        int tmp = idx >> 3;
        int lane = tmp & 63;
        int t2 = tmp >> 6;
        int ct = t2 & 15;
        int ks = t2 >> 4;
        int k = ks * 32 + (lane >> 4) * 8 + j;
        int colg = ct * 16 + (lane & 15);
        int g = colg >> 6, hd = colg & 63;
        float v;
        if (k < 128)      v = Wx[((g * 2 + 0) * 128 + k) * 64 + hd];
        else if (k < 192) v = Wh[((g * 2 + 0) * 64 + (k - 128)) * 64 + hd];
        else if (k < 320) v = Wx[((g * 2 + 1) * 128 + (k - 192)) * 64 + hd];
        else              v = Wh[((g * 2 + 1) * 64 + (k - 320)) * 64 + hd];
        Wp[idx] = f2bf(v);
    }
}

// ---- scan1: per-block (1024 elems) exclusive scan + block sums --------------
__global__ __launch_bounds__(256) void scan1_kernel(const int* __restrict__ cnt,
                                                    int* __restrict__ rowptr,
                                                    int* __restrict__ bsum, int n, int N) {
    __shared__ int sdata[256];
    int b = blockIdx.x, t = threadIdx.x;
    int base = b * 1024 + t * 4;
    int v[4];
    int tsum = 0;
#pragma unroll
    for (int j = 0; j < 4; ++j) {
        int idx = base + j;
        v[j] = (idx < N) ? cnt[idx] : 0;
        tsum += v[j];
    }
    sdata[t] = tsum;
    __syncthreads();
    for (int off = 1; off < 256; off <<= 1) {
        int tmp = (t >= off) ? sdata[t - off] : 0;
        __syncthreads();
        sdata[t] += tmp;
        __syncthreads();
    }
    if (t == 255) bsum[b] = sdata[255];
    int run = sdata[t] - tsum;
#pragma unroll
    for (int j = 0; j < 4; ++j) {
        int idx = base + j;
        if (idx < n) rowptr[idx] = run;
        run += v[j];
    }
}

// ---- scan_add: merged scan2+scan3. Each block's 256-range lies inside one
// 1024-chunk, so its offset = sum(bsum[0..grp-1]) — computed by wave reduction.
__global__ __launch_bounds__(256) void scan_add_kernel(int* __restrict__ rowptr,
                                                       const int* __restrict__ bsum, int n) {
    int b = blockIdx.x;
    int grp = (b * 256) >> 10;          // constant across the block
    int l = threadIdx.x & 63;
    int v = (l < grp) ? bsum[l] : 0;    // grp <= 48 < 64
#pragma unroll
    for (int off = 32; off; off >>= 1) v += __shfl_xor(v, off);
    int i = b * 256 + threadIdx.x;
    if (i < n) rowptr[i] += v;
}

// ---- fill CSR (atomic-free): eprm[pos] = {src, nrm} -------------------------
__global__ void fill_kernel(const int* __restrict__ src, const int* __restrict__ dst,
                            const float* __restrict__ ew, const float* __restrict__ deg,
                            const int* __restrict__ rowptr, const int* __restrict__ rank,
                            int2* __restrict__ eprm, int E) {
    int e = blockIdx.x * blockDim.x + threadIdx.x;
    if (e < E) {
        int d = dst[e];
        int s = src[e];
        float ds = deg[s], dd = deg[d];
        float dis = ds > 0.f ? rsqrtf(ds) : 0.f;
        float did = dd > 0.f ? rsqrtf(dd) : 0.f;
        float nrm = -dis * ew[e] * did;
        int pos = rowptr[d] + rank[e];
        eprm[pos] = make_int2(s, __float_as_int(nrm));
    }
}

// ---- gather: 4 nodes per wave, 16 lanes per node, eprm chunk prefetch -------
__global__ __launch_bounds__(256) void gather_kernel(const int* __restrict__ rowptr,
                                                     const int2* __restrict__ eprm,
                                                     const ushort_t* __restrict__ xb,
                                                     const ushort_t* __restrict__ hb,
                                                     ushort_t* __restrict__ Txb,
                                                     ushort_t* __restrict__ Thb, int N) {
    int lane = threadIdx.x & 63;
    int wave = threadIdx.x >> 6;
    int grp = lane >> 4, l16 = lane & 15;
    int node = blockIdx.x * 16 + wave * 4 + grp;
    bool valid = node < N;
    int p = 0, end = 0;
    if (valid) { p = rowptr[node]; end = rowptr[node + 1]; }

    float ax[8] = {0.f, 0.f, 0.f, 0.f, 0.f, 0.f, 0.f, 0.f};
    float ah[4] = {0.f, 0.f, 0.f, 0.f};

    int idx0 = p + l16;
    int2 pr = (idx0 < end) ? eprm[idx0] : make_int2(0, 0);

    for (int base = p; base < end; base += 16) {
        int2 cur = pr;
        int nidx = base + 16 + l16;
        if (base + 16 < end) pr = (nidx < end) ? eprm[nidx] : make_int2(0, 0);
        int sv = cur.x;
        float wv = __int_as_float(cur.y);
        int mcount = end - base; if (mcount > 16) mcount = 16;
        int sl0 = grp * 16;
        int j = 0;
        for (; j + 4 <= mcount; j += 4) {
            int s0 = __shfl(sv, sl0 + j + 0), s1 = __shfl(sv, sl0 + j + 1);
            int s2 = __shfl(sv, sl0 + j + 2), s3 = __shfl(sv, sl0 + j + 3);
            float w0 = __shfl(wv, sl0 + j + 0), w1 = __shfl(wv, sl0 + j + 1);
            float w2 = __shfl(wv, sl0 + j + 2), w3 = __shfl(wv, sl0 + j + 3);
            short8 xv0 = *(const short8*)(xb + (size_t)s0 * 128 + l16 * 8);
            short8 xv1 = *(const short8*)(xb + (size_t)s1 * 128 + l16 * 8);
            short8 xv2 = *(const short8*)(xb + (size_t)s2 * 128 + l16 * 8);
            short8 xv3 = *(const short8*)(xb + (size_t)s3 * 128 + l16 * 8);
            short4v hv0 = *(const short4v*)(hb + (size_t)s0 * 64 + l16 * 4);
            short4v hv1 = *(const short4v*)(hb + (size_t)s1 * 64 + l16 * 4);
            short4v hv2 = *(const short4v*)(hb + (size_t)s2 * 64 + l16 * 4);
            short4v hv3 = *(const short4v*)(hb + (size_t)s3 * 64 + l16 * 4);
#pragma unroll
            for (int i = 0; i < 8; ++i)
                ax[i] += w0 * bf2f_s(xv0[i]) + w1 * bf2f_s(xv1[i])
                       + w2 * bf2f_s(xv2[i]) + w3 * bf2f_s(xv3[i]);
#pragma unroll
            for (int i = 0; i < 4; ++i)
                ah[i] += w0 * bf2f_s(hv0[i]) + w1 * bf2f_s(hv1[i])
                       + w2 * bf2f_s(hv2[i]) + w3 * bf2f_s(hv3[i]);
        }
        for (; j < mcount; ++j) {
            int s0 = __shfl(sv, sl0 + j);
            float w0 = __shfl(wv, sl0 + j);
            short8 xv0 = *(const short8*)(xb + (size_t)s0 * 128 + l16 * 8);
            short4v hv0 = *(const short4v*)(hb + (size_t)s0 * 64 + l16 * 4);
#pragma unroll
            for (int i = 0; i < 8; ++i) ax[i] += w0 * bf2f_s(xv0[i]);
#pragma unroll
            for (int i = 0; i < 4; ++i) ah[i] += w0 * bf2f_s(hv0[i]);
        }
    }

    if (valid) {
        short8 tx;
#pragma unroll
        for (int i = 0; i < 8; ++i) tx[i] = (short)f2bf(ax[i]);
        *(short8*)(Txb + (size_t)node * 128 + l16 * 8) = tx;
        short4v th;
#pragma unroll
        for (int i = 0; i < 4; ++i) th[i] = (short)f2bf(ah[i]);
        *(short4v*)(Thb + (size_t)node * 64 + l16 * 4) = th;
    }
}

// ---- fused MFMA GEMM + LSTM gates + head, LDS-shared B (double-buffered) ----
__global__ __launch_bounds__(256, 4) void fused_mfma(
    const ushort_t* __restrict__ xb, const ushort_t* __restrict__ hb,
    const ushort_t* __restrict__ Txb, const ushort_t* __restrict__ Thb,
    const float* __restrict__ c_in, const ushort_t* __restrict__ Wp,
    const float* __restrict__ bx, const float* __restrict__ bh,
    const float* __restrict__ wc, const float* __restrict__ bg,
    const float* __restrict__ Whead, const float* __restrict__ bhead,
    float* __restrict__ out, int N) {
    __shared__ ushort_t Bs[2][8192];  // 2 x 16 KB ks-tiles
    int tid = threadIdx.x;
    int lane = tid & 63;
    int wave = tid >> 6;
    int quad = lane >> 4, m = lane & 15;
    int row0 = (blockIdx.x * 4 + wave) * 16;
    int ar = row0 + m; if (ar >= N) ar = N - 1;

    {
        const float4* gsrc = (const float4*)(Wp);
        float4* ldst = (float4*)Bs[0];
#pragma unroll
        for (int i = 0; i < 4; ++i) ldst[tid + 256 * i] = gsrc[tid + 256 * i];
    }

    f32x4 acc[16];
#pragma unroll
    for (int ct = 0; ct < 16; ++ct) {
        int g = ct >> 2, hd = (ct & 3) * 16 + m;
        float b = bx[g * 64 + hd] + bh[g * 64 + hd];
        f32x4 bb = {b, b, b, b};
        acc[ct] = bb;
    }

    int ko = quad * 8;
    __syncthreads();

#pragma unroll
    for (int ks = 0; ks < 12; ++ks) {
        int buf = ks & 1;
        float4 tmp[4];
        if (ks < 11) {
            const float4* gsrc = (const float4*)(Wp + (ks + 1) * 8192);
#pragma unroll
            for (int i = 0; i < 4; ++i) tmp[i] = gsrc[tid + 256 * i];
        }
        const ushort_t* a;
        if (ks < 4)       a = xb  + (size_t)ar * 128 + ks * 32 + ko;
        else if (ks < 6)  a = hb  + (size_t)ar * 64 + (ks - 4) * 32 + ko;
        else if (ks < 10) a = Txb + (size_t)ar * 128 + (ks - 6) * 32 + ko;
        else              a = Thb + (size_t)ar * 64 + (ks - 10) * 32 + ko;
        short8 af = *(const short8*)a;
        const short8* bsp = (const short8*)Bs[buf];
#pragma unroll
        for (int ct = 0; ct < 16; ++ct) {
            short8 bf = bsp[ct * 64 + lane];
            acc[ct] = __builtin_amdgcn_mfma_f32_16x16x32_bf16(af, bf, acc[ct], 0, 0, 0);
        }
        if (ks < 11) {
            float4* ldst = (float4*)Bs[buf ^ 1];
#pragma unroll
            for (int i = 0; i < 4; ++i) ldst[tid + 256 * i] = tmp[i];
            __syncthreads();
        }
    }

    float hp[4] = {0.f, 0.f, 0.f, 0.f};
    float bhv = bhead[0];

#pragma unroll
    for (int hs = 0; hs < 4; ++hs) {
        int hd = hs * 16 + m;
        float wc0 = wc[hd], wc1 = wc[64 + hd], wc2 = wc[128 + hd];
        float bg0 = bg[hd], bg1 = bg[64 + hd], bg2 = bg[128 + hd], bg3 = bg[192 + hd];
        float wh = Whead[hd];
#pragma unroll
        for (int reg = 0; reg < 4; ++reg) {
            int n = row0 + quad * 4 + reg;
            if (n < N) {
                float c_old = c_in[(size_t)n * 64 + hd];
                float zi = acc[0 * 4 + hs][reg];
                float zf = acc[1 * 4 + hs][reg];
                float zg = acc[2 * 4 + hs][reg];
                float zo = acc[3 * 4 + hs][reg];
                float ii = fsig(zi + wc0 * c_old + bg0);
                float ff = fsig(zf + wc1 * c_old + bg1);
                float gg = ftanh(zg + bg2);
                float cn = ff * c_old + ii * gg;
                float oo = fsig(zo + wc2 * cn + bg3);
                float hn = oo * ftanh(cn);
                out[N + (size_t)n * 64 + hd] = hn;
                out[N + (size_t)N * 64 + (size_t)n * 64 + hd] = cn;
                float lr = hn > 0.f ? hn : NEG_SLOPE * hn;
                hp[reg] += lr * wh;
            }
        }
    }
#pragma unroll
    for (int reg = 0; reg < 4; ++reg) {
        float v0 = hp[reg];
#pragma unroll
        for (int mask = 1; mask < 16; mask <<= 1) v0 += __shfl_xor(v0, mask);
        if (m == 0) {
            int n0_ = row0 + quad * 4 + reg;
            if (n0_ < N) out[n0_] = v0 + bhv;
        }
    }
}

extern "C" void kernel_launch(void* const* d_in, const int* in_sizes, int n_in,
                              void* d_out, int out_size, void* d_ws, size_t ws_size,
                              hipStream_t stream) {
    const float* x = (const float*)d_in[0];
    const int* ei = (const int*)d_in[1];
    const float* ew = (const float*)d_in[2];
    const float* h = (const float*)d_in[3];
    const float* c = (const float*)d_in[4];
    const float* Wx = (const float*)d_in[5];
    const float* bx = (const float*)d_in[6];
    const float* Wh = (const float*)d_in[7];
    const float* bh = (const float*)d_in[8];
    const float* wc = (const float*)d_in[9];
    const float* bg = (const float*)d_in[10];
    const float* Whead = (const float*)d_in[11];
    const float* bhead = (const float*)d_in[12];

    int N = in_sizes[0] / IN_DIM;  // 50000
    int E = in_sizes[1] / 2;       // 800000
    const int* src = ei;
    const int* dst = ei + E;

    char* wp = (char*)d_ws;
    auto alloc = [&](size_t bytes) {
        char* p = wp;
        wp += (bytes + 255) & ~(size_t)255;
        return p;
    };
    float* deg = (float*)alloc((size_t)2 * N * 4);  // deg | cnt contiguous for memset
    int* cnt = (int*)(deg + N);
    int* rank = (int*)alloc((size_t)E * 4);
    int* rowptr = (int*)alloc((size_t)(N + 2) * 4);
    int* bsum = (int*)alloc(64 * 4);
    int2* eprm = (int2*)alloc((size_t)E * 8);
    ushort_t* xb = (ushort_t*)alloc((size_t)N * 128 * 2);
    ushort_t* hb = (ushort_t*)alloc((size_t)N * 64 * 2);
    ushort_t* Txb = (ushort_t*)alloc((size_t)N * 128 * 2);
    ushort_t* Thb = (ushort_t*)alloc((size_t)N * 64 * 2);
    ushort_t* Wp = (ushort_t*)alloc((size_t)384 * 256 * 2);

    hipMemsetAsync(deg, 0, (size_t)2 * N * sizeof(float), stream);

    int nScan = N + 1;
    int nBlocksScan = (nScan + 1023) / 1024;

    prep_kernel<<<(E + 255) / 256, 256, 0, stream>>>(src, dst, ew, x, h, Wx, Wh,
                                                     deg, cnt, rank, (uint_t*)xb, (uint_t*)hb,
                                                     Wp, E, N);
    scan1_kernel<<<nBlocksScan, 256, 0, stream>>>(cnt, rowptr, bsum, nScan, N);
    scan_add_kernel<<<(nScan + 255) / 256, 256, 0, stream>>>(rowptr, bsum, nScan);
    fill_kernel<<<(E + 255) / 256, 256, 0, stream>>>(src, dst, ew, deg, rowptr, rank, eprm, E);
    gather_kernel<<<(N + 15) / 16, 256, 0, stream>>>(rowptr, eprm, xb, hb, Txb, Thb, N);
    fused_mfma<<<(N + 63) / 64, 256, 0, stream>>>(xb, hb, Txb, Thb, c, Wp, bx, bh, wc, bg,
                                                  Whead, bhead, (float*)d_out, N);
}